// Round 1
// baseline (245.724 us; speedup 1.0000x reference)
//
#include <hip/hip_runtime.h>
#include <math.h>

#define NN 20000
#define NE 320000
#define FIN 4
#define TP 12
#define OC 256
#define HIDN 128
#define OD 12
#define FT 48            // FIN*TP
#define NPB 8            // nodes per block in the fused kernel

// workspace layout (float indices)
#define OFF_FLAG  0
#define OFF_DEG   64
#define OFF_DINV  (OFF_DEG + NN)
#define OFF_P     (OFF_DINV + NN)
#define OFF_MZ    (OFF_P + NN*FT)
#define OFF_MH    (OFF_MZ + FIN*OC)
#define OFF_CZ    (OFF_MH + FIN*OC)
#define OFF_CH    (OFF_CZ + OC)
#define OFF_PROBS (OFF_CH + OC)

// ---- detect whether edge_index arrived as int64 or int32 ----
__global__ void detect_kernel(const unsigned long long* ei, int* flag) {
    __shared__ int sbad;
    if (threadIdx.x == 0) sbad = 0;
    __syncthreads();
    int bad = 0;
    for (int i = threadIdx.x; i < 2048; i += 256) {
        unsigned long long v = ei[i];       // first 2048 int64 slots (within src row either way)
        if (v >= (unsigned long long)NN) bad = 1;
    }
    if (bad) sbad = 1;
    __syncthreads();
    if (threadIdx.x == 0) *flag = (sbad == 0) ? 1 : 0;  // 1 => int64
}

__device__ __forceinline__ int load_idx(const void* ei, int is64, long off) {
    return is64 ? (int)((const long long*)ei)[off] : ((const int*)ei)[off];
}

// ---- weighted degree (edges + self loops) ----
__global__ void deg_kernel(const void* ei, const float* w, const int* flag, float* deg) {
    int i = blockIdx.x * blockDim.x + threadIdx.x;
    int is64 = *flag;
    if (i < NE) {
        int dst = load_idx(ei, is64, (long)NE + i);
        atomicAdd(&deg[dst], w[i]);
    } else {
        int n = i - NE;
        if (n < NN) atomicAdd(&deg[n], 1.0f);
    }
}

__global__ void dinv_kernel(const float* deg, float* dinv) {
    int i = blockIdx.x * blockDim.x + threadIdx.x;
    if (i < NN) {
        float d = deg[i];
        dinv[i] = d > 0.0f ? 1.0f / sqrtf(d) : 0.0f;
    }
}

// ---- P = A @ X : init with self-loop contribution, then edge scatter ----
__global__ void initP_kernel(const float* x, const float* dinv, float* P) {
    int i = blockIdx.x * blockDim.x + threadIdx.x;
    if (i < NN * FT) {
        int n = i / FT;
        float di = dinv[n];
        P[i] = di * di * x[i];
    }
}

__global__ void scatter_kernel(const void* ei, const float* w, const int* flag,
                               const float* dinv, const float* x, float* P) {
    int idx = blockIdx.x * blockDim.x + threadIdx.x;
    if (idx >= NE * FT) return;
    int e = idx / FT;
    int k = idx - e * FT;
    int is64 = *flag;
    int src = load_idx(ei, is64, e);
    int dst = load_idx(ei, is64, (long)NE + e);
    float nrm = dinv[src] * w[e] * dinv[dst];
    atomicAdd(&P[dst * FT + k], nrm * x[src * FT + k]);
}

// ---- fold weight chains: Mz = Wz@Lzw[:256], cz = bz@Lzw[:256]+Lzb (same for h); probs ----
__global__ void smallmats_kernel(const float* Wz, const float* bz,
                                 const float* Wh, const float* bh,
                                 const float* Lzw, const float* Lzb,
                                 const float* Lhw, const float* Lhb,
                                 const float* att,
                                 float* Mz, float* Mh, float* cz, float* ch, float* probs) {
    int c = threadIdx.x;  // 0..255
    float az0 = 0, az1 = 0, az2 = 0, az3 = 0, abz = 0;
    float ah0 = 0, ah1 = 0, ah2 = 0, ah3 = 0, abh = 0;
    for (int k = 0; k < OC; ++k) {
        float lz = Lzw[k * OC + c];
        float lh = Lhw[k * OC + c];
        az0 += Wz[k] * lz;
        az1 += Wz[OC + k] * lz;
        az2 += Wz[2 * OC + k] * lz;
        az3 += Wz[3 * OC + k] * lz;
        abz += bz[k] * lz;
        ah0 += Wh[k] * lh;
        ah1 += Wh[OC + k] * lh;
        ah2 += Wh[2 * OC + k] * lh;
        ah3 += Wh[3 * OC + k] * lh;
        abh += bh[k] * lh;
    }
    Mz[c] = az0; Mz[OC + c] = az1; Mz[2 * OC + c] = az2; Mz[3 * OC + c] = az3;
    Mh[c] = ah0; Mh[OC + c] = ah1; Mh[2 * OC + c] = ah2; Mh[3 * OC + c] = ah3;
    cz[c] = abz + Lzb[c];
    ch[c] = abh + Lhb[c];
    if (c == 0) {
        float m = att[0];
        for (int t = 1; t < TP; ++t) m = fmaxf(m, att[t]);
        float s = 0.0f, e[TP];
        for (int t = 0; t < TP; ++t) { e[t] = expf(att[t] - m); s += e[t]; }
        for (int t = 0; t < TP; ++t) probs[t] = e[t] / s;
    }
}

// ---- fused per-node: gated accumulation over T + output MLP ----
__global__ __launch_bounds__(256) void main_kernel(
    const float* __restrict__ P, const float* __restrict__ Mz, const float* __restrict__ Mh,
    const float* __restrict__ cz, const float* __restrict__ ch, const float* __restrict__ probs,
    const float* __restrict__ W1, const float* __restrict__ b1,
    const float* __restrict__ W2, const float* __restrict__ b2,
    float* __restrict__ out) {
    int c = threadIdx.x;
    int nb = blockIdx.x * NPB;
    __shared__ float shp[NPB * FT];
    __shared__ float shpr[TP];
    __shared__ float shh[NPB][OC];
    __shared__ float shh1[NPB][HIDN];

    for (int i = c; i < NPB * FT; i += 256) shp[i] = P[nb * FT + i];
    if (c < TP) shpr[c] = probs[c];
    float mz0 = Mz[c], mz1 = Mz[OC + c], mz2 = Mz[2 * OC + c], mz3 = Mz[3 * OC + c];
    float mh0 = Mh[c], mh1 = Mh[OC + c], mh2 = Mh[2 * OC + c], mh3 = Mh[3 * OC + c];
    float czc = cz[c], chc = ch[c];
    __syncthreads();

    for (int m = 0; m < NPB; ++m) {
        float hacc = 0.0f;
#pragma unroll
        for (int t = 0; t < TP; ++t) {
            float p0 = shp[m * FT + t];
            float p1 = shp[m * FT + 12 + t];
            float p2 = shp[m * FT + 24 + t];
            float p3 = shp[m * FT + 36 + t];
            float az = czc + p0 * mz0 + p1 * mz1 + p2 * mz2 + p3 * mz3;
            float ah = chc + p0 * mh0 + p1 * mh1 + p2 * mh2 + p3 * mh3;
            float z = 1.0f / (1.0f + __expf(-az));
            float e2 = __expf(2.0f * ah);
            float ht = 1.0f - 2.0f / (e2 + 1.0f);   // tanh, NaN-safe at +/-inf
            hacc += shpr[t] * (1.0f - z) * ht;
        }
        out[NN * OD + (nb + m) * OC + c] = hacc;    // out_hidden
        shh[m][c] = fmaxf(hacc, 0.0f);
    }
    __syncthreads();

    // layer 1: 256 threads = (half: 4 nodes) x (j: 128 hidden)
    {
        int j = c & (HIDN - 1);
        int m0 = (c >> 7) * 4;
        float s0 = 0, s1 = 0, s2 = 0, s3 = 0;
        for (int k = 0; k < OC; ++k) {
            float w = W1[k * HIDN + j];
            s0 += shh[m0 + 0][k] * w;
            s1 += shh[m0 + 1][k] * w;
            s2 += shh[m0 + 2][k] * w;
            s3 += shh[m0 + 3][k] * w;
        }
        float bb = b1[j];
        shh1[m0 + 0][j] = fmaxf(s0 + bb, 0.0f);
        shh1[m0 + 1][j] = fmaxf(s1 + bb, 0.0f);
        shh1[m0 + 2][j] = fmaxf(s2 + bb, 0.0f);
        shh1[m0 + 3][j] = fmaxf(s3 + bb, 0.0f);
    }
    __syncthreads();

    // layer 2: 96 active threads = 8 nodes x 12 outputs
    if (c < NPB * OD) {
        int m = c / OD;
        int k = c - m * OD;
        float a = b2[k];
        for (int j = 0; j < HIDN; ++j) a += shh1[m][j] * W2[j * OD + k];
        out[(nb + m) * OD + k] = a;
    }
}

extern "C" void kernel_launch(void* const* d_in, const int* in_sizes, int n_in,
                              void* d_out, int out_size, void* d_ws, size_t ws_size,
                              hipStream_t stream) {
    const float* x   = (const float*)d_in[0];
    const void*  ei  = d_in[1];
    const float* ea  = (const float*)d_in[2];
    const float* att = (const float*)d_in[3];
    const float* Wz  = (const float*)d_in[4];
    const float* bz  = (const float*)d_in[5];
    // d_in[6], d_in[7] (Wr, br) dead: Hzero*R == 0 in the reference
    const float* Wh  = (const float*)d_in[8];
    const float* bh  = (const float*)d_in[9];
    const float* Lzw = (const float*)d_in[10];
    const float* Lzb = (const float*)d_in[11];
    // d_in[12], d_in[13] (Lrw, Lrb) dead
    const float* Lhw = (const float*)d_in[14];
    const float* Lhb = (const float*)d_in[15];
    const float* W1  = (const float*)d_in[16];
    const float* b1  = (const float*)d_in[17];
    const float* W2  = (const float*)d_in[18];
    const float* b2  = (const float*)d_in[19];

    float* out = (float*)d_out;
    float* ws  = (float*)d_ws;

    int*   flag  = (int*)(ws + OFF_FLAG);
    float* deg   = ws + OFF_DEG;
    float* dinv  = ws + OFF_DINV;
    float* P     = ws + OFF_P;
    float* Mz    = ws + OFF_MZ;
    float* Mh    = ws + OFF_MH;
    float* cz    = ws + OFF_CZ;
    float* ch    = ws + OFF_CH;
    float* probs = ws + OFF_PROBS;

    detect_kernel<<<1, 256, 0, stream>>>((const unsigned long long*)ei, flag);
    hipMemsetAsync(deg, 0, NN * sizeof(float), stream);
    deg_kernel<<<(NE + NN + 255) / 256, 256, 0, stream>>>(ei, ea, flag, deg);
    dinv_kernel<<<(NN + 255) / 256, 256, 0, stream>>>(deg, dinv);
    initP_kernel<<<(NN * FT + 255) / 256, 256, 0, stream>>>(x, dinv, P);
    scatter_kernel<<<(NE * FT + 255) / 256, 256, 0, stream>>>(ei, ea, flag, dinv, x, P);
    smallmats_kernel<<<1, 256, 0, stream>>>(Wz, bz, Wh, bh, Lzw, Lzb, Lhw, Lhb, att,
                                            Mz, Mh, cz, ch, probs);
    main_kernel<<<NN / NPB, 256, 0, stream>>>(P, Mz, Mh, cz, ch, probs, W1, b1, W2, b2, out);
}